// Round 4
// baseline (123.211 us; speedup 1.0000x reference)
//
#include <hip/hip_runtime.h>
#include <hip/hip_bf16.h>

// Problem constants (fixed by setup_inputs): B=64, T=1024, C=768, CK=64, R=256
#define BB 64
#define TT 1024
#define CC 768
#define CKK 64
#define SS 512   // T/2
#define RR 256
#define TOUT 768 // R + S
#define ASTRIDE 68  // 64 + 4 pad: 16B-aligned, stride mod 32 = 4 -> 2-way max

// ---------------------------------------------------------------------------
// Kernel 1: register-tiled max-GEMM. scores[s,d] = dot(k[2s], k[2d+1]).
// Grid: 64 batches x 8 row-strips (64 rows) = 512 blocks, 256 threads.
// Block loops over 4 col-tiles of 128. Thread (tx,ty) owns rows ty+16i (i<4),
// cols ct*128 + tx+16j (j<8). LDS 52KB -> 2 blocks/CU, 8 waves/CU for latency
// hiding. Per-row (max, argmax-first) as packed u64 (mapped<<32)|(511-d) in
// registers; cross-tx max via 4 shfl_xor; lane tx==0 writes nodekey.
// ---------------------------------------------------------------------------
__global__ __launch_bounds__(256) void score_kernel(
    const float* __restrict__ k, unsigned long long* __restrict__ nodekey) {
  const int b  = blockIdx.x >> 3;
  const int rt = blockIdx.x & 7;
  const int t  = threadIdx.x;
  const int tx = t & 15, ty = t >> 4;

  __shared__ float As[64 * ASTRIDE];
  __shared__ float Bs[128 * ASTRIDE];

  // stage A strip (64 even tokens) once: 1024 float4, 4 per thread
#pragma unroll
  for (int l = 0; l < 4; ++l) {
    int f = t + l * 256;
    int row = f >> 4, c4 = f & 15;
    float4 va = ((const float4*)(k + ((size_t)b * TT + 2 * (rt * 64 + row)) * CKK))[c4];
    *(float4*)(&As[row * ASTRIDE + c4 * 4]) = va;
  }

  unsigned long long rkey[4];
#pragma unroll
  for (int i = 0; i < 4; ++i) rkey[i] = 0ull;

  for (int ct = 0; ct < 4; ++ct) {
    __syncthreads();  // previous compute done (and A staged, first iter)
#pragma unroll
    for (int l = 0; l < 8; ++l) {
      int f = t + l * 256;
      int row = f >> 4, c4 = f & 15;
      float4 vb = ((const float4*)(k + ((size_t)b * TT + 2 * (ct * 128 + row) + 1) * CKK))[c4];
      *(float4*)(&Bs[row * ASTRIDE + c4 * 4]) = vb;
    }
    __syncthreads();

    float acc[4][8];
#pragma unroll
    for (int i = 0; i < 4; ++i)
#pragma unroll
      for (int j = 0; j < 8; ++j) acc[i][j] = 0.f;

    for (int k4 = 0; k4 < 16; ++k4) {
      float4 av[4], bv[8];
#pragma unroll
      for (int i = 0; i < 4; ++i)
        av[i] = *(const float4*)(&As[(ty + 16 * i) * ASTRIDE + k4 * 4]);
#pragma unroll
      for (int j = 0; j < 8; ++j)
        bv[j] = *(const float4*)(&Bs[(tx + 16 * j) * ASTRIDE + k4 * 4]);
#pragma unroll
      for (int i = 0; i < 4; ++i)
#pragma unroll
        for (int j = 0; j < 8; ++j) {
          acc[i][j] += av[i].x * bv[j].x;
          acc[i][j] += av[i].y * bv[j].y;
          acc[i][j] += av[i].z * bv[j].z;
          acc[i][j] += av[i].w * bv[j].w;
        }
    }

    // fold this col-tile into the per-row running keys
#pragma unroll
    for (int i = 0; i < 4; ++i) {
      float mx = acc[i][0];
      int mj = 0;
#pragma unroll
      for (int j = 1; j < 8; ++j)
        if (acc[i][j] > mx) { mx = acc[i][j]; mj = j; }  // asc d: > keeps min d
      int d = ct * 128 + tx + 16 * mj;
      unsigned int u = __float_as_uint(mx);
      unsigned int mapped = (u & 0x80000000u) ? ~u : (u | 0x80000000u);
      unsigned long long key =
          ((unsigned long long)mapped << 32) | (unsigned int)(SS - 1 - d);
      if (key > rkey[i]) rkey[i] = key;
    }
  }

  // reduce across the 16 col-lanes (same ty -> 16 consecutive lanes in wave)
#pragma unroll
  for (int i = 0; i < 4; ++i) {
#pragma unroll
    for (int off = 1; off < 16; off <<= 1) {
      unsigned long long o = __shfl_xor(rkey[i], off);
      if (o > rkey[i]) rkey[i] = o;
    }
  }
  if (tx == 0) {
#pragma unroll
    for (int i = 0; i < 4; ++i)
      nodekey[b * SS + rt * 64 + ty + 16 * i] = rkey[i];
  }
}

// ---------------------------------------------------------------------------
// Kernel 2: per-batch stable descending argsort via hybrid bitonic sort on
// 64-bit keys (~mapped<<32 | index): stages with j<=32 are intra-wave
// shfl_xor (no barrier), only j>=64 goes through LDS (6 stages).
// Then build per-dst linked lists (head/nxt) inverting the src->dst scatter.
// ---------------------------------------------------------------------------
__global__ __launch_bounds__(512) void sort_kernel(
    const unsigned long long* __restrict__ nodekey,
    int* __restrict__ unm_idx, int* __restrict__ src_idx,
    int* __restrict__ head, int* __restrict__ nxt) {
  const int b = blockIdx.x;
  const int i = threadIdx.x;
  __shared__ unsigned long long key[SS];
  __shared__ int nodeidx[SS];
  __shared__ int headS[SS];
  __shared__ int nxtS[RR];

  unsigned long long nk = nodekey[b * SS + i];
  unsigned int mapped;
  int nidx;
  if (i == 0) {  // scores[:,0,:] forced to NEG_INF -> max=-1e30, argmax=0
    mapped = ~__float_as_uint(-1e30f);
    nidx = 0;
  } else {
    mapped = (unsigned int)(nk >> 32);
    nidx = SS - 1 - (int)(nk & 0xffffffffu);
  }
  nodeidx[i] = nidx;
  headS[i] = -1;
  unsigned long long my = ((unsigned long long)(~mapped) << 32) | (unsigned int)i;

  for (int kk = 2; kk <= SS; kk <<= 1) {
    for (int j = kk >> 1; j > 0; j >>= 1) {
      bool up = ((i & kk) == 0);
      bool lower = ((i & j) == 0);
      bool takeMin = (up == lower);
      unsigned long long partner;
      if (j >= 64) {
        key[i] = my;
        __syncthreads();
        partner = key[i ^ j];
        __syncthreads();
      } else {
        partner = __shfl_xor(my, j);
      }
      bool pSmaller = partner < my;
      my = (takeMin == pSmaller) ? partner : my;
    }
  }
  key[i] = my;
  __syncthreads();

  int e = (int)(my & 0xffffffffu);
  if (i < RR) {
    src_idx[b * RR + i] = e;
    int d = nodeidx[e];
    nxtS[i] = atomicExch(&headS[d], i);
  } else {
    unm_idx[b * RR + (i - RR)] = e;
  }
  __syncthreads();
  head[b * SS + i] = headS[i];
  if (i < RR) nxt[b * RR + i] = nxtS[i];
}

// ---------------------------------------------------------------------------
// Kernel 3: fused output assembly, one wave per 768-float row, 4 rows per
// 256-thread block. Lane l handles float4 elements l, l+64, l+128 (1KB per
// wave instruction, fully coalesced). Chain walk is wave-uniform.
//  rows [0,R):   out = x[2*unm_idx[p]]
//  rows [R,768): out = x[2*d+1] + sum over chain of x[2*src_idx[i]]
// ---------------------------------------------------------------------------
__global__ __launch_bounds__(256) void gather_kernel(
    const float* __restrict__ x, const int* __restrict__ unm_idx,
    const int* __restrict__ src_idx, const int* __restrict__ head,
    const int* __restrict__ nxt, float* __restrict__ out) {
  const int w = threadIdx.x >> 6;   // wave in block
  const int l = threadIdx.x & 63;   // lane
  const int pg = blockIdx.x * 4 + w;
  const int b = pg / TOUT;
  const int p = pg % TOUT;
  float4* dst = (float4*)(out + ((size_t)b * TOUT + p) * CC);

  if (p < RR) {
    int srow = 2 * __builtin_amdgcn_readfirstlane(unm_idx[b * RR + p]);
    const float4* s = (const float4*)(x + ((size_t)b * TT + srow) * CC);
    float4 a0 = s[l], a1 = s[l + 64], a2 = s[l + 128];
    dst[l] = a0; dst[l + 64] = a1; dst[l + 128] = a2;
  } else {
    int d = p - RR;
    const float4* s0 = (const float4*)(x + ((size_t)b * TT + 2 * d + 1) * CC);
    float4 a0 = s0[l], a1 = s0[l + 64], a2 = s0[l + 128];
    for (int i = __builtin_amdgcn_readfirstlane(head[b * SS + d]); i >= 0;
         i = __builtin_amdgcn_readfirstlane(nxt[b * RR + i])) {
      int e = __builtin_amdgcn_readfirstlane(src_idx[b * RR + i]);
      const float4* s = (const float4*)(x + ((size_t)b * TT + 2 * e) * CC);
      float4 v0 = s[l], v1 = s[l + 64], v2 = s[l + 128];
      a0.x += v0.x; a0.y += v0.y; a0.z += v0.z; a0.w += v0.w;
      a1.x += v1.x; a1.y += v1.y; a1.z += v1.z; a1.w += v1.w;
      a2.x += v2.x; a2.y += v2.y; a2.z += v2.z; a2.w += v2.w;
    }
    dst[l] = a0; dst[l + 64] = a1; dst[l + 128] = a2;
  }
}

extern "C" void kernel_launch(void* const* d_in, const int* in_sizes, int n_in,
                              void* d_out, int out_size, void* d_ws, size_t ws_size,
                              hipStream_t stream) {
  const float* x = (const float*)d_in[0];
  const float* k = (const float*)d_in[1];
  float* out = (float*)d_out;

  char* ws = (char*)d_ws;
  unsigned long long* nodekey = (unsigned long long*)(ws);  // 64*512*8 = 262144
  int* unm_idx = (int*)(ws + 262144);                       // 64*256*4 =  65536
  int* src_idx = (int*)(ws + 327680);                       //             65536
  int* head    = (int*)(ws + 393216);                       // 64*512*4 = 131072
  int* nxt     = (int*)(ws + 524288);                       //             65536
                                                            // total 589824 B

  score_kernel<<<BB * 8, 256, 0, stream>>>(k, nodekey);
  sort_kernel<<<BB, SS, 0, stream>>>(nodekey, unm_idx, src_idx, head, nxt);
  gather_kernel<<<BB * TOUT / 4, 256, 0, stream>>>(x, unm_idx, src_idx, head, nxt, out);
}

// Round 5
// 103.252 us; speedup vs baseline: 1.1933x; 1.1933x over previous
//
#include <hip/hip_runtime.h>
#include <hip/hip_bf16.h>

// Problem constants (fixed by setup_inputs): B=64, T=1024, C=768, CK=64, R=256
#define BB 64
#define TT 1024
#define CC 768
#define CKK 64
#define SS 512   // T/2
#define RR 256
#define TOUT 768 // R + S
#define ASTRIDE 68  // 64 + 4 pad: 16B-aligned, stride mod 32 = 4 -> 2-way max
#define NSCORE (BB * 8)       // 512 score blocks
#define NCOPY  (BB * SS / 4)  // 8192 copy blocks (wave per row, 4 rows/block)

// ---------------------------------------------------------------------------
// Kernel 1 (fused by block range):
//  blocks [0, NSCORE): register-tiled max-GEMM scores[s,d]=dot(k[2s],k[2d+1])
//    64-row strip per block, loops 4 col-tiles of 128; per-row (max, argmax)
//    as packed u64 (mapped<<32)|(511-d) in regs; shfl_xor reduce; write nodekey.
//  blocks [NSCORE, NSCORE+NCOPY): dst-base copy out[b][R+d] = x[b][2d+1],
//    one wave per 768-float row. Sort-independent 200MB of traffic overlapped
//    under score's VALU time (VMEM vs VALU waves co-schedule on a CU).
// ---------------------------------------------------------------------------
__global__ __launch_bounds__(256) void score_copy_kernel(
    const float* __restrict__ k, const float* __restrict__ x,
    float* __restrict__ out, unsigned long long* __restrict__ nodekey) {
  const int bid = blockIdx.x;
  const int t = threadIdx.x;

  if (bid >= NSCORE) {
    // ---- dst-base copy path ----
    const int w = t >> 6, l = t & 63;
    const int rowg = (bid - NSCORE) * 4 + w;
    const int b = rowg >> 9;          // /512
    const int d = rowg & 511;
    const float4* s = (const float4*)(x + ((size_t)b * TT + 2 * d + 1) * CC);
    float4* dst = (float4*)(out + ((size_t)b * TOUT + RR + d) * CC);
    float4 a0 = s[l], a1 = s[l + 64], a2 = s[l + 128];
    dst[l] = a0; dst[l + 64] = a1; dst[l + 128] = a2;
    return;
  }

  // ---- score path ----
  const int b  = bid >> 3;
  const int rt = bid & 7;
  const int tx = t & 15, ty = t >> 4;

  __shared__ float As[64 * ASTRIDE];
  __shared__ float Bs[128 * ASTRIDE];

#pragma unroll
  for (int l = 0; l < 4; ++l) {
    int f = t + l * 256;
    int row = f >> 4, c4 = f & 15;
    float4 va = ((const float4*)(k + ((size_t)b * TT + 2 * (rt * 64 + row)) * CKK))[c4];
    *(float4*)(&As[row * ASTRIDE + c4 * 4]) = va;
  }

  unsigned long long rkey[4];
#pragma unroll
  for (int i = 0; i < 4; ++i) rkey[i] = 0ull;

  for (int ct = 0; ct < 4; ++ct) {
    __syncthreads();
#pragma unroll
    for (int l = 0; l < 8; ++l) {
      int f = t + l * 256;
      int row = f >> 4, c4 = f & 15;
      float4 vb = ((const float4*)(k + ((size_t)b * TT + 2 * (ct * 128 + row) + 1) * CKK))[c4];
      *(float4*)(&Bs[row * ASTRIDE + c4 * 4]) = vb;
    }
    __syncthreads();

    float acc[4][8];
#pragma unroll
    for (int i = 0; i < 4; ++i)
#pragma unroll
      for (int j = 0; j < 8; ++j) acc[i][j] = 0.f;

    for (int k4 = 0; k4 < 16; ++k4) {
      float4 av[4], bv[8];
#pragma unroll
      for (int i = 0; i < 4; ++i)
        av[i] = *(const float4*)(&As[(ty + 16 * i) * ASTRIDE + k4 * 4]);
#pragma unroll
      for (int j = 0; j < 8; ++j)
        bv[j] = *(const float4*)(&Bs[(tx + 16 * j) * ASTRIDE + k4 * 4]);
#pragma unroll
      for (int i = 0; i < 4; ++i)
#pragma unroll
        for (int j = 0; j < 8; ++j) {
          acc[i][j] += av[i].x * bv[j].x;
          acc[i][j] += av[i].y * bv[j].y;
          acc[i][j] += av[i].z * bv[j].z;
          acc[i][j] += av[i].w * bv[j].w;
        }
    }

#pragma unroll
    for (int i = 0; i < 4; ++i) {
      float mx = acc[i][0];
      int mj = 0;
#pragma unroll
      for (int j = 1; j < 8; ++j)
        if (acc[i][j] > mx) { mx = acc[i][j]; mj = j; }  // asc d: > keeps min d
      int d = ct * 128 + tx + 16 * mj;
      unsigned int u = __float_as_uint(mx);
      unsigned int mapped = (u & 0x80000000u) ? ~u : (u | 0x80000000u);
      unsigned long long key =
          ((unsigned long long)mapped << 32) | (unsigned int)(SS - 1 - d);
      if (key > rkey[i]) rkey[i] = key;
    }
  }

#pragma unroll
  for (int i = 0; i < 4; ++i) {
#pragma unroll
    for (int off = 1; off < 16; off <<= 1) {
      unsigned long long o = __shfl_xor(rkey[i], off);
      if (o > rkey[i]) rkey[i] = o;
    }
  }
  if (tx == 0) {
#pragma unroll
    for (int i = 0; i < 4; ++i)
      nodekey[b * SS + rt * 64 + ty + 16 * i] = rkey[i];
  }
}

// ---------------------------------------------------------------------------
// Kernel 2: per-batch stable descending argsort via hybrid bitonic sort on
// 64-bit keys (~mapped<<32 | index): j<=32 stages intra-wave shfl_xor,
// j>=64 through LDS. Then invert src->dst scatter into head/nxt lists.
// ---------------------------------------------------------------------------
__global__ __launch_bounds__(512) void sort_kernel(
    const unsigned long long* __restrict__ nodekey,
    int* __restrict__ unm_idx, int* __restrict__ src_idx,
    int* __restrict__ head, int* __restrict__ nxt) {
  const int b = blockIdx.x;
  const int i = threadIdx.x;
  __shared__ unsigned long long key[SS];
  __shared__ int nodeidx[SS];
  __shared__ int headS[SS];
  __shared__ int nxtS[RR];

  unsigned long long nk = nodekey[b * SS + i];
  unsigned int mapped;
  int nidx;
  if (i == 0) {  // scores[:,0,:] forced to NEG_INF -> max=-1e30, argmax=0
    mapped = ~__float_as_uint(-1e30f);
    nidx = 0;
  } else {
    mapped = (unsigned int)(nk >> 32);
    nidx = SS - 1 - (int)(nk & 0xffffffffu);
  }
  nodeidx[i] = nidx;
  headS[i] = -1;
  unsigned long long my = ((unsigned long long)(~mapped) << 32) | (unsigned int)i;

  for (int kk = 2; kk <= SS; kk <<= 1) {
    for (int j = kk >> 1; j > 0; j >>= 1) {
      bool up = ((i & kk) == 0);
      bool lower = ((i & j) == 0);
      bool takeMin = (up == lower);
      unsigned long long partner;
      if (j >= 64) {
        key[i] = my;
        __syncthreads();
        partner = key[i ^ j];
        __syncthreads();
      } else {
        partner = __shfl_xor(my, j);
      }
      bool pSmaller = partner < my;
      my = (takeMin == pSmaller) ? partner : my;
    }
  }
  __syncthreads();  // key[] reads done in last LDS stage

  int e = (int)(my & 0xffffffffu);
  if (i < RR) {
    src_idx[b * RR + i] = e;
    int d = nodeidx[e];
    nxtS[i] = atomicExch(&headS[d], i);
  } else {
    unm_idx[b * RR + (i - RR)] = e;
  }
  __syncthreads();
  head[b * SS + i] = headS[i];
  if (i < RR) nxt[b * RR + i] = nxtS[i];
}

// ---------------------------------------------------------------------------
// Kernel 3: remainder assembly, one wave per row, 4 rows per 256-thread block.
//  rows [0,R):   out = x[2*unm_idx[p]]                    (always)
//  rows [R,768): only if chain non-empty: out = x[2*d+1] + sum chain rows;
//                empty-chain waves exit after one (L2) head load — base row
//                was already written by K1's copy blocks.
// ---------------------------------------------------------------------------
__global__ __launch_bounds__(256) void gather_kernel(
    const float* __restrict__ x, const int* __restrict__ unm_idx,
    const int* __restrict__ src_idx, const int* __restrict__ head,
    const int* __restrict__ nxt, float* __restrict__ out) {
  const int w = threadIdx.x >> 6;
  const int l = threadIdx.x & 63;
  const int pg = blockIdx.x * 4 + w;
  const int b = pg / TOUT;
  const int p = pg % TOUT;
  float4* dst = (float4*)(out + ((size_t)b * TOUT + p) * CC);

  if (p < RR) {
    int srow = 2 * __builtin_amdgcn_readfirstlane(unm_idx[b * RR + p]);
    const float4* s = (const float4*)(x + ((size_t)b * TT + srow) * CC);
    float4 a0 = s[l], a1 = s[l + 64], a2 = s[l + 128];
    dst[l] = a0; dst[l + 64] = a1; dst[l + 128] = a2;
  } else {
    int d = p - RR;
    int h = __builtin_amdgcn_readfirstlane(head[b * SS + d]);
    if (h < 0) return;  // base row already correct from K1
    const float4* s0 = (const float4*)(x + ((size_t)b * TT + 2 * d + 1) * CC);
    float4 a0 = s0[l], a1 = s0[l + 64], a2 = s0[l + 128];
    for (int i = h; i >= 0; i = __builtin_amdgcn_readfirstlane(nxt[b * RR + i])) {
      int e = __builtin_amdgcn_readfirstlane(src_idx[b * RR + i]);
      const float4* s = (const float4*)(x + ((size_t)b * TT + 2 * e) * CC);
      float4 v0 = s[l], v1 = s[l + 64], v2 = s[l + 128];
      a0.x += v0.x; a0.y += v0.y; a0.z += v0.z; a0.w += v0.w;
      a1.x += v1.x; a1.y += v1.y; a1.z += v1.z; a1.w += v1.w;
      a2.x += v2.x; a2.y += v2.y; a2.z += v2.z; a2.w += v2.w;
    }
    dst[l] = a0; dst[l + 64] = a1; dst[l + 128] = a2;
  }
}

extern "C" void kernel_launch(void* const* d_in, const int* in_sizes, int n_in,
                              void* d_out, int out_size, void* d_ws, size_t ws_size,
                              hipStream_t stream) {
  const float* x = (const float*)d_in[0];
  const float* k = (const float*)d_in[1];
  float* out = (float*)d_out;

  char* ws = (char*)d_ws;
  unsigned long long* nodekey = (unsigned long long*)(ws);  // 64*512*8 = 262144
  int* unm_idx = (int*)(ws + 262144);                       // 64*256*4 =  65536
  int* src_idx = (int*)(ws + 327680);                       //             65536
  int* head    = (int*)(ws + 393216);                       // 64*512*4 = 131072
  int* nxt     = (int*)(ws + 524288);                       //             65536
                                                            // total 589824 B

  score_copy_kernel<<<NSCORE + NCOPY, 256, 0, stream>>>(k, x, out, nodekey);
  sort_kernel<<<BB, SS, 0, stream>>>(nodekey, unm_idx, src_idx, head, nxt);
  gather_kernel<<<BB * TOUT / 4, 256, 0, stream>>>(x, unm_idx, src_idx, head, nxt, out);
}

// Round 6
// 101.312 us; speedup vs baseline: 1.2162x; 1.0192x over previous
//
#include <hip/hip_runtime.h>
#include <hip/hip_bf16.h>

// Problem constants (fixed by setup_inputs): B=64, T=1024, C=768, CK=64, R=256
#define BB 64
#define TT 1024
#define CC 768
#define CKK 64
#define SS 512   // T/2
#define RR 256
#define TOUT 768 // R + S
#define ASTRIDE 68  // 64 + 4 pad: 16B-aligned, stride mod 32 = 4 -> 2-way max
#define NSCORE (BB * 8)       // 512 score blocks
#define NCOPY  (BB * SS / 4)  // 8192 copy blocks (wave per row, 4 rows/block)

// ---------------------------------------------------------------------------
// Kernel 1 (fused by block range):
//  blocks [0, NSCORE): register-tiled max-GEMM scores[s,d]=dot(k[2s],k[2d+1]).
//    XCD-clustered mapping: blockIdx%8 == batch%8, so all 8 row-strips of a
//    batch share one XCD's L2 -> B-panel (odd k rows) fetched ~once per batch
//    instead of 8x from HBM.
//  blocks [NSCORE, ...): dst-base copy out[b][R+d] = x[b][2d+1], wave per row,
//    overlapped under score's VALU time (VMEM vs VALU waves co-schedule).
// ---------------------------------------------------------------------------
__global__ __launch_bounds__(256) void score_copy_kernel(
    const float* __restrict__ k, const float* __restrict__ x,
    float* __restrict__ out, unsigned long long* __restrict__ nodekey) {
  const int bid = blockIdx.x;
  const int t = threadIdx.x;

  if (bid >= NSCORE) {
    // ---- dst-base copy path ----
    const int w = t >> 6, l = t & 63;
    const int rowg = (bid - NSCORE) * 4 + w;
    const int b = rowg >> 9;          // /512
    const int d = rowg & 511;
    const float4* s = (const float4*)(x + ((size_t)b * TT + 2 * d + 1) * CC);
    float4* dst = (float4*)(out + ((size_t)b * TOUT + RR + d) * CC);
    float4 a0 = s[l], a1 = s[l + 64], a2 = s[l + 128];
    dst[l] = a0; dst[l + 64] = a1; dst[l + 128] = a2;
    return;
  }

  // ---- score path: batch-clustered remap (bijective on [0,512)) ----
  // bid = (b/8)*64 + rt*8 + (b%8)  ->  bid%8 = b%8 (same XCD per batch)
  const int low3 = bid & 7;
  const int g = bid >> 3;
  const int rt = g & 7;
  const int b = (g >> 3) * 8 + low3;
  const int tx = t & 15, ty = t >> 4;

  __shared__ float As[64 * ASTRIDE];
  __shared__ float Bs[128 * ASTRIDE];

#pragma unroll
  for (int l = 0; l < 4; ++l) {
    int f = t + l * 256;
    int row = f >> 4, c4 = f & 15;
    float4 va = ((const float4*)(k + ((size_t)b * TT + 2 * (rt * 64 + row)) * CKK))[c4];
    *(float4*)(&As[row * ASTRIDE + c4 * 4]) = va;
  }

  unsigned long long rkey[4];
#pragma unroll
  for (int i = 0; i < 4; ++i) rkey[i] = 0ull;

  for (int ct = 0; ct < 4; ++ct) {
    __syncthreads();
#pragma unroll
    for (int l = 0; l < 8; ++l) {
      int f = t + l * 256;
      int row = f >> 4, c4 = f & 15;
      float4 vb = ((const float4*)(k + ((size_t)b * TT + 2 * (ct * 128 + row) + 1) * CKK))[c4];
      *(float4*)(&Bs[row * ASTRIDE + c4 * 4]) = vb;
    }
    __syncthreads();

    float acc[4][8];
#pragma unroll
    for (int i = 0; i < 4; ++i)
#pragma unroll
      for (int j = 0; j < 8; ++j) acc[i][j] = 0.f;

    for (int k4 = 0; k4 < 16; ++k4) {
      float4 av[4], bv[8];
#pragma unroll
      for (int i = 0; i < 4; ++i)
        av[i] = *(const float4*)(&As[(ty + 16 * i) * ASTRIDE + k4 * 4]);
#pragma unroll
      for (int j = 0; j < 8; ++j)
        bv[j] = *(const float4*)(&Bs[(tx + 16 * j) * ASTRIDE + k4 * 4]);
#pragma unroll
      for (int i = 0; i < 4; ++i)
#pragma unroll
        for (int j = 0; j < 8; ++j) {
          acc[i][j] += av[i].x * bv[j].x;
          acc[i][j] += av[i].y * bv[j].y;
          acc[i][j] += av[i].z * bv[j].z;
          acc[i][j] += av[i].w * bv[j].w;
        }
    }

#pragma unroll
    for (int i = 0; i < 4; ++i) {
      float mx = acc[i][0];
      int mj = 0;
#pragma unroll
      for (int j = 1; j < 8; ++j)
        if (acc[i][j] > mx) { mx = acc[i][j]; mj = j; }  // asc d: > keeps min d
      int d = ct * 128 + tx + 16 * mj;
      unsigned int u = __float_as_uint(mx);
      unsigned int mapped = (u & 0x80000000u) ? ~u : (u | 0x80000000u);
      unsigned long long key =
          ((unsigned long long)mapped << 32) | (unsigned int)(SS - 1 - d);
      if (key > rkey[i]) rkey[i] = key;
    }
  }

#pragma unroll
  for (int i = 0; i < 4; ++i) {
#pragma unroll
    for (int off = 1; off < 16; off <<= 1) {
      unsigned long long o = __shfl_xor(rkey[i], off);
      if (o > rkey[i]) rkey[i] = o;
    }
  }
  if (tx == 0) {
#pragma unroll
    for (int i = 0; i < 4; ++i)
      nodekey[b * SS + rt * 64 + ty + 16 * i] = rkey[i];
  }
}

// ---------------------------------------------------------------------------
// Kernel 2: per-batch stable descending argsort (hybrid bitonic: j<=32 via
// shfl_xor, j>=64 via LDS), then invert src->dst scatter into a packed
// per-dst descriptor  info = cnt | e0<<9 | csr_off<<18  plus a CSR src array
// (chain walk + 512-wide LDS scan). K3's common case needs ONE info load.
// ---------------------------------------------------------------------------
__global__ __launch_bounds__(512) void sort_kernel(
    const unsigned long long* __restrict__ nodekey,
    int* __restrict__ unm_idx, int* __restrict__ dstinfo,
    int* __restrict__ csr) {
  const int b = blockIdx.x;
  const int i = threadIdx.x;
  __shared__ unsigned long long key[SS];
  __shared__ int nodeidx[SS];
  __shared__ int headS[SS];
  __shared__ int nxtS[RR];
  __shared__ int eS[RR];
  __shared__ int sc[SS];

  unsigned long long nk = nodekey[b * SS + i];
  unsigned int mapped;
  int nidx;
  if (i == 0) {  // scores[:,0,:] forced to NEG_INF -> max=-1e30, argmax=0
    mapped = ~__float_as_uint(-1e30f);
    nidx = 0;
  } else {
    mapped = (unsigned int)(nk >> 32);
    nidx = SS - 1 - (int)(nk & 0xffffffffu);
  }
  nodeidx[i] = nidx;
  headS[i] = -1;
  unsigned long long my = ((unsigned long long)(~mapped) << 32) | (unsigned int)i;

  for (int kk = 2; kk <= SS; kk <<= 1) {
    for (int j = kk >> 1; j > 0; j >>= 1) {
      bool up = ((i & kk) == 0);
      bool lower = ((i & j) == 0);
      bool takeMin = (up == lower);
      unsigned long long partner;
      if (j >= 64) {
        key[i] = my;
        __syncthreads();
        partner = key[i ^ j];
        __syncthreads();
      } else {
        partner = __shfl_xor(my, j);
      }
      bool pSmaller = partner < my;
      my = (takeMin == pSmaller) ? partner : my;
    }
  }
  __syncthreads();

  int e = (int)(my & 0xffffffffu);
  if (i < RR) {
    eS[i] = e;
    int d = nodeidx[e];
    nxtS[i] = atomicExch(&headS[d], i);
  } else {
    unm_idx[b * RR + (i - RR)] = e;
  }
  __syncthreads();

  // thread i == dst row d: walk chain, count
  int cnt = 0;
  for (int it = headS[i]; it >= 0; it = nxtS[it]) ++cnt;
  sc[i] = cnt;
  __syncthreads();
  // Hillis-Steele inclusive scan over 512
  for (int ofs = 1; ofs < SS; ofs <<= 1) {
    int v = sc[i];
    int vn = (i >= ofs) ? sc[i - ofs] : 0;
    __syncthreads();
    sc[i] = v + vn;
    __syncthreads();
  }
  int off = sc[i] - cnt;  // exclusive
  int j = 0;
  for (int it = headS[i]; it >= 0; it = nxtS[it]) csr[b * RR + off + (j++)] = eS[it];
  int e0 = (cnt > 0) ? eS[headS[i]] : 0;
  dstinfo[b * SS + i] = cnt | (e0 << 9) | (off << 18);
}

// ---------------------------------------------------------------------------
// Kernel 3: remainder assembly, one wave per row, 4 rows per 256-thread block.
//  rows [0,R):   out = x[2*unm_idx[p]]
//  rows [R,768): if cnt>0: out = x[2*d+1] + x[2*e0] + sum extra CSR rows;
//                cnt==0 waves exit after one int load (base written by K1).
// ---------------------------------------------------------------------------
__global__ __launch_bounds__(256) void gather_kernel(
    const float* __restrict__ x, const int* __restrict__ unm_idx,
    const int* __restrict__ dstinfo, const int* __restrict__ csr,
    float* __restrict__ out) {
  const int w = threadIdx.x >> 6;
  const int l = threadIdx.x & 63;
  const int pg = blockIdx.x * 4 + w;
  const int b = pg / TOUT;
  const int p = pg % TOUT;
  float4* dst = (float4*)(out + ((size_t)b * TOUT + p) * CC);

  if (p < RR) {
    int srow = 2 * __builtin_amdgcn_readfirstlane(unm_idx[b * RR + p]);
    const float4* s = (const float4*)(x + ((size_t)b * TT + srow) * CC);
    float4 a0 = s[l], a1 = s[l + 64], a2 = s[l + 128];
    dst[l] = a0; dst[l + 64] = a1; dst[l + 128] = a2;
  } else {
    int d = p - RR;
    int info = __builtin_amdgcn_readfirstlane(dstinfo[b * SS + d]);
    int cnt = info & 511;
    if (cnt == 0) return;  // base row already correct from K1
    int e0 = (info >> 9) & 511;
    int off = (info >> 18) & 511;
    const float4* s0 = (const float4*)(x + ((size_t)b * TT + 2 * d + 1) * CC);
    const float4* s1 = (const float4*)(x + ((size_t)b * TT + 2 * e0) * CC);
    float4 a0 = s0[l], a1 = s0[l + 64], a2 = s0[l + 128];
    float4 v0 = s1[l], v1 = s1[l + 64], v2 = s1[l + 128];
    a0.x += v0.x; a0.y += v0.y; a0.z += v0.z; a0.w += v0.w;
    a1.x += v1.x; a1.y += v1.y; a1.z += v1.z; a1.w += v1.w;
    a2.x += v2.x; a2.y += v2.y; a2.z += v2.z; a2.w += v2.w;
    for (int j = 1; j < cnt; ++j) {
      int e = __builtin_amdgcn_readfirstlane(csr[b * RR + off + j]);
      const float4* s = (const float4*)(x + ((size_t)b * TT + 2 * e) * CC);
      float4 u0 = s[l], u1 = s[l + 64], u2 = s[l + 128];
      a0.x += u0.x; a0.y += u0.y; a0.z += u0.z; a0.w += u0.w;
      a1.x += u1.x; a1.y += u1.y; a1.z += u1.z; a1.w += u1.w;
      a2.x += u2.x; a2.y += u2.y; a2.z += u2.z; a2.w += u2.w;
    }
    dst[l] = a0; dst[l + 64] = a1; dst[l + 128] = a2;
  }
}

extern "C" void kernel_launch(void* const* d_in, const int* in_sizes, int n_in,
                              void* d_out, int out_size, void* d_ws, size_t ws_size,
                              hipStream_t stream) {
  const float* x = (const float*)d_in[0];
  const float* k = (const float*)d_in[1];
  float* out = (float*)d_out;

  char* ws = (char*)d_ws;
  unsigned long long* nodekey = (unsigned long long*)(ws);  // 64*512*8 = 262144
  int* unm_idx = (int*)(ws + 262144);                       // 64*256*4 =  65536
  int* dstinfo = (int*)(ws + 327680);                       // 64*512*4 = 131072
  int* csr     = (int*)(ws + 458752);                       // 64*256*4 =  65536
                                                            // total 524288 B

  score_copy_kernel<<<NSCORE + NCOPY, 256, 0, stream>>>(k, x, out, nodekey);
  sort_kernel<<<BB, SS, 0, stream>>>(nodekey, unm_idx, dstinfo, csr);
  gather_kernel<<<BB * TOUT / 4, 256, 0, stream>>>(x, unm_idx, dstinfo, csr, out);
}

// Round 7
// 100.619 us; speedup vs baseline: 1.2245x; 1.0069x over previous
//
#include <hip/hip_runtime.h>
#include <hip/hip_bf16.h>

// Problem constants (fixed by setup_inputs): B=64, T=1024, C=768, CK=64, R=256
#define BB 64
#define TT 1024
#define CC 768
#define CKK 64
#define SS 512   // T/2
#define RR 256
#define TOUT 768 // R + S
#define ASTRIDE 68  // 64 + 4 pad: 16B-aligned, stride mod 32 = 4 -> 2-way max
#define NSCORE (BB * 8)       // 512 score blocks
#define NCOPY  (BB * SS / 4)  // 8192 copy blocks (wave per row, 4 rows/block)
#define HALFROWS (BB * TOUT / 2)  // 24576

typedef float v4f __attribute__((ext_vector_type(4)));

// ---------------------------------------------------------------------------
// Kernel 1 (fused by block range):
//  blocks [0, NSCORE): register-tiled max-GEMM scores[s,d]=dot(k[2s],k[2d+1]).
//    XCD-clustered mapping: blockIdx%8 == batch%8 -> B-panel L2 reuse per XCD.
//  blocks [NSCORE, ...): dst-base copy out[b][R+d] = x[b][2d+1], wave per row.
//    Non-temporal loads/stores: x_odd read once ever; protects L2 for k reuse.
// ---------------------------------------------------------------------------
__global__ __launch_bounds__(256) void score_copy_kernel(
    const float* __restrict__ k, const float* __restrict__ x,
    float* __restrict__ out, unsigned long long* __restrict__ nodekey) {
  const int bid = blockIdx.x;
  const int t = threadIdx.x;

  if (bid >= NSCORE) {
    // ---- dst-base copy path ----
    const int w = t >> 6, l = t & 63;
    const int rowg = (bid - NSCORE) * 4 + w;
    const int b = rowg >> 9;          // /512
    const int d = rowg & 511;
    const v4f* s = (const v4f*)(x + ((size_t)b * TT + 2 * d + 1) * CC);
    v4f* dst = (v4f*)(out + ((size_t)b * TOUT + RR + d) * CC);
    v4f a0 = __builtin_nontemporal_load(s + l);
    v4f a1 = __builtin_nontemporal_load(s + l + 64);
    v4f a2 = __builtin_nontemporal_load(s + l + 128);
    __builtin_nontemporal_store(a0, dst + l);
    __builtin_nontemporal_store(a1, dst + l + 64);
    __builtin_nontemporal_store(a2, dst + l + 128);
    return;
  }

  // ---- score path: batch-clustered remap (bijective on [0,512)) ----
  const int low3 = bid & 7;
  const int g = bid >> 3;
  const int rt = g & 7;
  const int b = (g >> 3) * 8 + low3;
  const int tx = t & 15, ty = t >> 4;

  __shared__ float As[64 * ASTRIDE];
  __shared__ float Bs[128 * ASTRIDE];

#pragma unroll
  for (int l = 0; l < 4; ++l) {
    int f = t + l * 256;
    int row = f >> 4, c4 = f & 15;
    float4 va = ((const float4*)(k + ((size_t)b * TT + 2 * (rt * 64 + row)) * CKK))[c4];
    *(float4*)(&As[row * ASTRIDE + c4 * 4]) = va;
  }

  unsigned long long rkey[4];
#pragma unroll
  for (int i = 0; i < 4; ++i) rkey[i] = 0ull;

  for (int ct = 0; ct < 4; ++ct) {
    __syncthreads();
#pragma unroll
    for (int l = 0; l < 8; ++l) {
      int f = t + l * 256;
      int row = f >> 4, c4 = f & 15;
      float4 vb = ((const float4*)(k + ((size_t)b * TT + 2 * (ct * 128 + row) + 1) * CKK))[c4];
      *(float4*)(&Bs[row * ASTRIDE + c4 * 4]) = vb;
    }
    __syncthreads();

    float acc[4][8];
#pragma unroll
    for (int i = 0; i < 4; ++i)
#pragma unroll
      for (int j = 0; j < 8; ++j) acc[i][j] = 0.f;

    for (int k4 = 0; k4 < 16; ++k4) {
      float4 av[4], bv[8];
#pragma unroll
      for (int i = 0; i < 4; ++i)
        av[i] = *(const float4*)(&As[(ty + 16 * i) * ASTRIDE + k4 * 4]);
#pragma unroll
      for (int j = 0; j < 8; ++j)
        bv[j] = *(const float4*)(&Bs[(tx + 16 * j) * ASTRIDE + k4 * 4]);
#pragma unroll
      for (int i = 0; i < 4; ++i)
#pragma unroll
        for (int j = 0; j < 8; ++j) {
          acc[i][j] += av[i].x * bv[j].x;
          acc[i][j] += av[i].y * bv[j].y;
          acc[i][j] += av[i].z * bv[j].z;
          acc[i][j] += av[i].w * bv[j].w;
        }
    }

#pragma unroll
    for (int i = 0; i < 4; ++i) {
      float mx = acc[i][0];
      int mj = 0;
#pragma unroll
      for (int j = 1; j < 8; ++j)
        if (acc[i][j] > mx) { mx = acc[i][j]; mj = j; }  // asc d: > keeps min d
      int d = ct * 128 + tx + 16 * mj;
      unsigned int u = __float_as_uint(mx);
      unsigned int mapped = (u & 0x80000000u) ? ~u : (u | 0x80000000u);
      unsigned long long key =
          ((unsigned long long)mapped << 32) | (unsigned int)(SS - 1 - d);
      if (key > rkey[i]) rkey[i] = key;
    }
  }

#pragma unroll
  for (int i = 0; i < 4; ++i) {
#pragma unroll
    for (int off = 1; off < 16; off <<= 1) {
      unsigned long long o = __shfl_xor(rkey[i], off);
      if (o > rkey[i]) rkey[i] = o;
    }
  }
  if (tx == 0) {
#pragma unroll
    for (int i = 0; i < 4; ++i)
      nodekey[b * SS + rt * 64 + ty + 16 * i] = rkey[i];
  }
}

// ---------------------------------------------------------------------------
// Kernel 2: per-batch stable descending argsort (hybrid bitonic: j<=32 via
// shfl_xor, j>=64 via LDS), then invert src->dst scatter into packed per-dst
// descriptor  info = cnt | e0<<9 | csr_off<<18  + CSR src array.
// Scan is wave-shfl + 8-partial combine (2 barriers instead of 18).
// ---------------------------------------------------------------------------
__global__ __launch_bounds__(512) void sort_kernel(
    const unsigned long long* __restrict__ nodekey,
    int* __restrict__ unm_idx, int* __restrict__ dstinfo,
    int* __restrict__ csr) {
  const int b = blockIdx.x;
  const int i = threadIdx.x;
  const int lane = i & 63, w = i >> 6;
  __shared__ unsigned long long key[SS];
  __shared__ int nodeidx[SS];
  __shared__ int headS[SS];
  __shared__ int nxtS[RR];
  __shared__ int eS[RR];
  __shared__ int wsum[8];

  unsigned long long nk = nodekey[b * SS + i];
  unsigned int mapped;
  int nidx;
  if (i == 0) {  // scores[:,0,:] forced to NEG_INF -> max=-1e30, argmax=0
    mapped = ~__float_as_uint(-1e30f);
    nidx = 0;
  } else {
    mapped = (unsigned int)(nk >> 32);
    nidx = SS - 1 - (int)(nk & 0xffffffffu);
  }
  nodeidx[i] = nidx;
  headS[i] = -1;
  unsigned long long my = ((unsigned long long)(~mapped) << 32) | (unsigned int)i;

  for (int kk = 2; kk <= SS; kk <<= 1) {
    for (int j = kk >> 1; j > 0; j >>= 1) {
      bool up = ((i & kk) == 0);
      bool lower = ((i & j) == 0);
      bool takeMin = (up == lower);
      unsigned long long partner;
      if (j >= 64) {
        key[i] = my;
        __syncthreads();
        partner = key[i ^ j];
        __syncthreads();
      } else {
        partner = __shfl_xor(my, j);
      }
      bool pSmaller = partner < my;
      my = (takeMin == pSmaller) ? partner : my;
    }
  }
  __syncthreads();

  int e = (int)(my & 0xffffffffu);
  if (i < RR) {
    eS[i] = e;
    int d = nodeidx[e];
    nxtS[i] = atomicExch(&headS[d], i);
  } else {
    unm_idx[b * RR + (i - RR)] = e;
  }
  __syncthreads();

  // thread i == dst row d: walk chain, count
  int cnt = 0;
  for (int it = headS[i]; it >= 0; it = nxtS[it]) ++cnt;

  // inclusive scan: wave-level shfl_up, then cross-wave partials
  int v = cnt;
#pragma unroll
  for (int o = 1; o < 64; o <<= 1) {
    int n = __shfl_up(v, o);
    if (lane >= o) v += n;
  }
  if (lane == 63) wsum[w] = v;
  __syncthreads();
  if (w == 0 && lane < 8) {
    int p = wsum[lane];
#pragma unroll
    for (int o = 1; o < 8; o <<= 1) {
      int n = __shfl_up(p, o);
      if (lane >= o) p += n;
    }
    wsum[lane] = p;
  }
  __syncthreads();
  int incl = v + (w > 0 ? wsum[w - 1] : 0);
  int off = incl - cnt;  // exclusive

  int j = 0;
  for (int it = headS[i]; it >= 0; it = nxtS[it]) csr[b * RR + off + (j++)] = eS[it];
  int e0 = (cnt > 0) ? eS[headS[i]] : 0;
  dstinfo[b * SS + i] = cnt | (e0 << 9) | (off << 18);
}

// ---------------------------------------------------------------------------
// Kernel 3: remainder assembly. Each wave processes TWO distant rows (double
// memory-level parallelism); all bulk traffic non-temporal (x even rows are
// read exactly once across the whole kernel: unm ∪ chain = all evens).
//  rows [0,R):   out = x[2*unm_idx[p]]
//  rows [R,768): if cnt>0: out = out_base + x[2*e0] + extra CSR rows
// ---------------------------------------------------------------------------
__device__ __forceinline__ void process_row(
    const float* __restrict__ x, const int* __restrict__ unm_idx,
    const int* __restrict__ dstinfo, const int* __restrict__ csr,
    float* __restrict__ out, int pg, int l) {
  const int b = pg / TOUT;
  const int p = pg % TOUT;
  v4f* dst = (v4f*)(out + ((size_t)b * TOUT + p) * CC);

  if (p < RR) {
    int srow = 2 * __builtin_amdgcn_readfirstlane(unm_idx[b * RR + p]);
    const v4f* s = (const v4f*)(x + ((size_t)b * TT + srow) * CC);
    v4f a0 = __builtin_nontemporal_load(s + l);
    v4f a1 = __builtin_nontemporal_load(s + l + 64);
    v4f a2 = __builtin_nontemporal_load(s + l + 128);
    __builtin_nontemporal_store(a0, dst + l);
    __builtin_nontemporal_store(a1, dst + l + 64);
    __builtin_nontemporal_store(a2, dst + l + 128);
  } else {
    int d = p - RR;
    int info = __builtin_amdgcn_readfirstlane(dstinfo[b * SS + d]);
    int cnt = info & 511;
    if (cnt == 0) return;  // base row already correct from K1
    int e0 = (info >> 9) & 511;
    int off = (info >> 18) & 511;
    const v4f* s0 = (const v4f*)(out + ((size_t)b * TOUT + p) * CC);  // base
    const v4f* s1 = (const v4f*)(x + ((size_t)b * TT + 2 * e0) * CC);
    v4f a0 = __builtin_nontemporal_load(s0 + l);
    v4f a1 = __builtin_nontemporal_load(s0 + l + 64);
    v4f a2 = __builtin_nontemporal_load(s0 + l + 128);
    v4f v0 = __builtin_nontemporal_load(s1 + l);
    v4f v1 = __builtin_nontemporal_load(s1 + l + 64);
    v4f v2 = __builtin_nontemporal_load(s1 + l + 128);
    a0 += v0; a1 += v1; a2 += v2;
    for (int j = 1; j < cnt; ++j) {
      int e = __builtin_amdgcn_readfirstlane(csr[b * RR + off + j]);
      const v4f* s = (const v4f*)(x + ((size_t)b * TT + 2 * e) * CC);
      v4f u0 = __builtin_nontemporal_load(s + l);
      v4f u1 = __builtin_nontemporal_load(s + l + 64);
      v4f u2 = __builtin_nontemporal_load(s + l + 128);
      a0 += u0; a1 += u1; a2 += u2;
    }
    __builtin_nontemporal_store(a0, dst + l);
    __builtin_nontemporal_store(a1, dst + l + 64);
    __builtin_nontemporal_store(a2, dst + l + 128);
  }
}

__global__ __launch_bounds__(256) void gather_kernel(
    const float* __restrict__ x, const int* __restrict__ unm_idx,
    const int* __restrict__ dstinfo, const int* __restrict__ csr,
    float* __restrict__ out) {
  const int w = threadIdx.x >> 6;
  const int l = threadIdx.x & 63;
  const int r1 = blockIdx.x * 4 + w;
  process_row(x, unm_idx, dstinfo, csr, out, r1, l);
  process_row(x, unm_idx, dstinfo, csr, out, r1 + HALFROWS, l);
}

extern "C" void kernel_launch(void* const* d_in, const int* in_sizes, int n_in,
                              void* d_out, int out_size, void* d_ws, size_t ws_size,
                              hipStream_t stream) {
  const float* x = (const float*)d_in[0];
  const float* k = (const float*)d_in[1];
  float* out = (float*)d_out;

  char* ws = (char*)d_ws;
  unsigned long long* nodekey = (unsigned long long*)(ws);  // 64*512*8 = 262144
  int* unm_idx = (int*)(ws + 262144);                       // 64*256*4 =  65536
  int* dstinfo = (int*)(ws + 327680);                       // 64*512*4 = 131072
  int* csr     = (int*)(ws + 458752);                       // 64*256*4 =  65536
                                                            // total 524288 B

  score_copy_kernel<<<NSCORE + NCOPY, 256, 0, stream>>>(k, x, out, nodekey);
  sort_kernel<<<BB, SS, 0, stream>>>(nodekey, unm_idx, dstinfo, csr);
  gather_kernel<<<HALFROWS / 4, 256, 0, stream>>>(x, unm_idx, dstinfo, csr, out);
}